// Round 1
// baseline (268.751 us; speedup 1.0000x reference)
//
#include <hip/hip_runtime.h>

#define D 64

// Kernel 1: Xp = X @ W   (X: [N,64] fp32, W: [64,64] fp32, Xp: [N,64] fp32)
// One wave per row. W staged in LDS (16 KB). Lane d computes Xp[row][d].
__global__ __launch_bounds__(256) void gemm_kernel(const float* __restrict__ X,
                                                   const float* __restrict__ W,
                                                   float* __restrict__ Xp,
                                                   int nNodes) {
    __shared__ float Ws[D][D];  // 16 KB; Ws[k][d], d stride-1 -> 2-way bank alias (free)
    int tid = threadIdx.x;
    for (int i = tid; i < D * D; i += 256) Ws[i / D][i % D] = W[i];
    __syncthreads();

    int lane = tid & 63;
    int row  = blockIdx.x * 4 + (tid >> 6);
    if (row >= nNodes) return;

    float xv = X[row * D + lane];   // lane d holds X[row][d]
    float acc = 0.f;
#pragma unroll
    for (int k = 0; k < D; ++k) {
        acc += __shfl(xv, k, 64) * Ws[k][lane];
    }
    Xp[row * D + lane] = acc;
}

// Kernel 2: one wave per destination node.
//   eStart/eEnd via binary search on sorted `row`.
//   out[node][d] = attn * sum_e dot(Xp[node], Xp[col[e]]) * Xp[col[e]][d]
// No atomics; single coalesced store per node.
__global__ __launch_bounds__(256) void agg_kernel(const float* __restrict__ Xp,
                                                  const int* __restrict__ row,
                                                  const int* __restrict__ col,
                                                  const float* __restrict__ attn_w,
                                                  float* __restrict__ out,
                                                  int nNodes, int nEdges) {
    int lane = threadIdx.x & 63;
    int node = (blockIdx.x * blockDim.x + threadIdx.x) >> 6;
    if (node >= nNodes) return;

    // lower_bound(row, node)
    int lo = 0, hi = nEdges;
    while (lo < hi) {
        int mid = (lo + hi) >> 1;
        if (row[mid] < node) lo = mid + 1; else hi = mid;
    }
    int eStart = lo;
    // lower_bound(row, node+1), starting from eStart
    hi = nEdges;
    while (lo < hi) {
        int mid = (lo + hi) >> 1;
        if (row[mid] < node + 1) lo = mid + 1; else hi = mid;
    }
    int eEnd = lo;

    float attn = attn_w[0];
    float xr = Xp[node * D + lane];   // dst feature, lane d holds dim d
    float acc = 0.f;

    // process edges in chunks of 64: one coalesced load of col indices,
    // then broadcast each index via shfl.
    for (int base = eStart; base < eEnd; base += 64) {
        int n = eEnd - base; if (n > 64) n = 64;
        int myE = base + lane;
        int cidx = (myE < eEnd) ? col[myE] : 0;
        for (int j = 0; j < n; ++j) {
            int c = __shfl(cidx, j, 64);
            float xc = Xp[c * D + lane];
            float p = xr * xc;
            // butterfly reduction over 64 lanes -> all lanes hold the dot
#pragma unroll
            for (int off = 32; off > 0; off >>= 1)
                p += __shfl_xor(p, off, 64);
            acc += p * xc;
        }
    }

    out[node * D + lane] = attn * acc;
}

extern "C" void kernel_launch(void* const* d_in, const int* in_sizes, int n_in,
                              void* d_out, int out_size, void* d_ws, size_t ws_size,
                              hipStream_t stream) {
    const float* X    = (const float*)d_in[0];
    const float* W    = (const float*)d_in[1];
    const float* attn = (const float*)d_in[2];
    const int*   row  = (const int*)d_in[3];
    const int*   col  = (const int*)d_in[4];
    float* out = (float*)d_out;
    float* Xp  = (float*)d_ws;          // nNodes*64 fp32 = 12.8 MB scratch

    int nNodes = in_sizes[0] / D;
    int nEdges = in_sizes[3];

    int gemmBlocks = (nNodes + 3) / 4;       // 4 rows (waves) per block
    gemm_kernel<<<gemmBlocks, 256, 0, stream>>>(X, W, Xp, nNodes);

    int aggBlocks = (nNodes + 3) / 4;        // 4 nodes (waves) per block
    agg_kernel<<<aggBlocks, 256, 0, stream>>>(Xp, row, col, attn, out, nNodes, nEdges);
}

// Round 2
// 177.983 us; speedup vs baseline: 1.5100x; 1.5100x over previous
//
#include <hip/hip_runtime.h>

#define D 64

// ---------------------------------------------------------------------------
// Kernel 1: Xp = X @ W. One wave per row (grid-stride). Lane d holds column d
// of W in 64 VGPRs; X row is read wave-uniformly (scalar loads) -> pure FMA.
// ---------------------------------------------------------------------------
__global__ __launch_bounds__(256) void gemm_kernel(const float* __restrict__ X,
                                                   const float* __restrict__ W,
                                                   float* __restrict__ Xp,
                                                   int nNodes) {
    int lane = threadIdx.x & 63;
    int wave = (blockIdx.x * 256 + threadIdx.x) >> 6;
    int nWaves = gridDim.x * 4;

    float w[D];
#pragma unroll
    for (int k = 0; k < D; ++k) w[k] = W[k * D + lane];   // coalesced, L2-hot

    for (int r = wave; r < nNodes; r += nWaves) {
        int row = __builtin_amdgcn_readfirstlane(r);      // force uniform -> s_load
        const float4* xr = (const float4*)(X + row * D);
        float acc = 0.f;
#pragma unroll
        for (int k4 = 0; k4 < D / 4; ++k4) {
            float4 xv = xr[k4];
            acc = fmaf(xv.x, w[4 * k4 + 0], acc);
            acc = fmaf(xv.y, w[4 * k4 + 1], acc);
            acc = fmaf(xv.z, w[4 * k4 + 2], acc);
            acc = fmaf(xv.w, w[4 * k4 + 3], acc);
        }
        Xp[row * D + lane] = acc;
    }
}

// ---------------------------------------------------------------------------
// Kernel 2: CSR row pointers from sorted `row`. rowptr[q] = first e with
// row[e] >= q. O(E) parallel, replaces 2 binary searches per node.
// ---------------------------------------------------------------------------
__global__ __launch_bounds__(256) void rowptr_kernel(const int* __restrict__ row,
                                                     int* __restrict__ rowptr,
                                                     int nNodes, int nEdges) {
    int e = blockIdx.x * 256 + threadIdx.x;
    if (e >= nEdges) return;
    int r = row[e];
    int rprev = (e == 0) ? -1 : row[e - 1];
    for (int q = rprev + 1; q <= r; ++q) rowptr[q] = e;
    if (e == nEdges - 1) {
        for (int q = r + 1; q <= nNodes; ++q) rowptr[q] = nEdges;
    }
}

// ---------------------------------------------------------------------------
// Kernel 3: SDDMM, edge-parallel. 16 lanes per edge; float4 partial dots;
// 4-step shfl_xor reduce within the 16-lane group. s[e] = attn * <Xp_r, Xp_c>.
// ---------------------------------------------------------------------------
__global__ __launch_bounds__(256) void sddmm_kernel(const float* __restrict__ Xp,
                                                    const int* __restrict__ row,
                                                    const int* __restrict__ col,
                                                    const float* __restrict__ attn_w,
                                                    float* __restrict__ s,
                                                    int nEdges) {
    int t = blockIdx.x * 256 + threadIdx.x;
    int e = t >> 4;
    int l = t & 15;
    if (e >= nEdges) return;
    int r = row[e];
    int c = col[e];
    float4 a = ((const float4*)(Xp + r * D))[l];
    float4 b = ((const float4*)(Xp + c * D))[l];
    float p = a.x * b.x + a.y * b.y + a.z * b.z + a.w * b.w;
#pragma unroll
    for (int off = 8; off > 0; off >>= 1)      // xor 8,4,2,1 stays inside 16-lane group
        p += __shfl_xor(p, off, 64);
    if (l == 0) s[e] = p * attn_w[0];
}

// ---------------------------------------------------------------------------
// Kernel 4: SpMM, one wave per destination node. rowptr gives the edge range
// directly. Per edge: 2 shfl broadcasts + 1 coalesced 256B gather + 1 FMA.
// No atomics, single coalesced store.
// ---------------------------------------------------------------------------
__global__ __launch_bounds__(256) void spmm_kernel(const float* __restrict__ Xp,
                                                   const int* __restrict__ rowptr,
                                                   const int* __restrict__ col,
                                                   const float* __restrict__ s,
                                                   float* __restrict__ out,
                                                   int nNodes) {
    int lane = threadIdx.x & 63;
    int node = (blockIdx.x * 256 + threadIdx.x) >> 6;
    if (node >= nNodes) return;

    int eStart = rowptr[node];
    int eEnd   = rowptr[node + 1];

    float acc = 0.f;
    for (int base = eStart; base < eEnd; base += 64) {
        int n = eEnd - base; if (n > 64) n = 64;
        int myE = base + lane;
        bool valid = myE < eEnd;
        int   cidx = valid ? col[myE] : 0;
        float sval = valid ? s[myE]  : 0.f;
        for (int j = 0; j < n; ++j) {
            int   c  = __shfl(cidx, j, 64);
            float sj = __shfl(sval, j, 64);
            acc = fmaf(sj, Xp[c * D + lane], acc);
        }
    }
    out[node * D + lane] = acc;
}

extern "C" void kernel_launch(void* const* d_in, const int* in_sizes, int n_in,
                              void* d_out, int out_size, void* d_ws, size_t ws_size,
                              hipStream_t stream) {
    const float* X    = (const float*)d_in[0];
    const float* W    = (const float*)d_in[1];
    const float* attn = (const float*)d_in[2];
    const int*   row  = (const int*)d_in[3];
    const int*   col  = (const int*)d_in[4];
    float* out = (float*)d_out;

    int nNodes = in_sizes[0] / D;
    int nEdges = in_sizes[3];

    // workspace layout: Xp [nNodes*D] | s [nEdges] | rowptr [nNodes+1]
    float* Xp     = (float*)d_ws;
    float* s      = Xp + (size_t)nNodes * D;
    int*   rowptr = (int*)(s + nEdges);

    gemm_kernel<<<2048, 256, 0, stream>>>(X, W, Xp, nNodes);
    rowptr_kernel<<<(nEdges + 255) / 256, 256, 0, stream>>>(row, rowptr, nNodes, nEdges);
    sddmm_kernel<<<(nEdges * 16 + 255) / 256, 256, 0, stream>>>(Xp, row, col, attn, s, nEdges);
    spmm_kernel<<<(nNodes + 3) / 4, 256, 0, stream>>>(Xp, rowptr, col, s, out, nNodes);
}

// Round 3
// 119.961 us; speedup vs baseline: 2.2403x; 1.4837x over previous
//
#include <hip/hip_runtime.h>

#define D 64

// ---------------------------------------------------------------------------
// Kernel 1: Xp = X @ W. One wave per row (grid-stride). Lane d holds column d
// of W in 64 VGPRs; X row is read wave-uniformly (scalar broadcast) -> pure FMA.
// ---------------------------------------------------------------------------
__global__ __launch_bounds__(256) void gemm_kernel(const float* __restrict__ X,
                                                   const float* __restrict__ W,
                                                   float* __restrict__ Xp,
                                                   int nNodes) {
    int lane = threadIdx.x & 63;
    int wave = (blockIdx.x * 256 + threadIdx.x) >> 6;
    int nWaves = gridDim.x * 4;

    float w[D];
#pragma unroll
    for (int k = 0; k < D; ++k) w[k] = W[k * D + lane];   // coalesced, L1/L2-hot

    for (int r = wave; r < nNodes; r += nWaves) {
        int row = __builtin_amdgcn_readfirstlane(r);      // uniform -> scalar loads
        const float4* xr = (const float4*)(X + (size_t)row * D);
        float acc = 0.f;
#pragma unroll
        for (int k4 = 0; k4 < D / 4; ++k4) {
            float4 xv = xr[k4];
            acc = fmaf(xv.x, w[4 * k4 + 0], acc);
            acc = fmaf(xv.y, w[4 * k4 + 1], acc);
            acc = fmaf(xv.z, w[4 * k4 + 2], acc);
            acc = fmaf(xv.w, w[4 * k4 + 3], acc);
        }
        Xp[(size_t)row * D + lane] = acc;
    }
}

// ---------------------------------------------------------------------------
// Kernel 2: CSR row pointers from sorted `row`. rowptr[q] = first e with
// row[e] >= q.
// ---------------------------------------------------------------------------
__global__ __launch_bounds__(256) void rowptr_kernel(const int* __restrict__ row,
                                                     int* __restrict__ rowptr,
                                                     int nNodes, int nEdges) {
    int e = blockIdx.x * 256 + threadIdx.x;
    if (e >= nEdges) return;
    int r = row[e];
    int rprev = (e == 0) ? -1 : row[e - 1];
    for (int q = rprev + 1; q <= r; ++q) rowptr[q] = e;
    if (e == nEdges - 1) {
        for (int q = r + 1; q <= nNodes; ++q) rowptr[q] = nEdges;
    }
}

// ---------------------------------------------------------------------------
// Kernel 3: fused SDDMM + SpMM. One wave per destination node.
// 4 groups x 16 lanes; each group owns one edge, each lane a float4 (4 dims).
// Per iteration: 8 edges (2-way unroll), gathered row reused for both the
// attention dot (4-step in-group butterfly) and the accumulate. No atomics.
// ---------------------------------------------------------------------------
__global__ __launch_bounds__(256) void fused_kernel(const float* __restrict__ Xp,
                                                    const int* __restrict__ rowptr,
                                                    const int* __restrict__ col,
                                                    const float* __restrict__ attn_w,
                                                    float* __restrict__ out,
                                                    int nNodes) {
    int lane = threadIdx.x & 63;
    int node = (blockIdx.x * 256 + threadIdx.x) >> 6;
    if (node >= nNodes) return;
    int g = lane >> 4;       // edge group 0..3
    int l = lane & 15;       // lane within group -> dims 4l..4l+3

    int eStart = rowptr[node];
    int eEnd   = rowptr[node + 1];
    float attn = attn_w[0];
    float4 xr = ((const float4*)(Xp + (size_t)node * D))[l];   // dst row segment

    float4 acc0 = make_float4(0.f, 0.f, 0.f, 0.f);
    float4 acc1 = make_float4(0.f, 0.f, 0.f, 0.f);

    for (int base = eStart; base < eEnd; base += 8) {
        int e0 = base + g;
        int e1 = base + 4 + g;
        bool v0 = e0 < eEnd;
        bool v1 = e1 < eEnd;
        int c0 = col[v0 ? e0 : eStart];          // safe index for masked lanes
        int c1 = col[v1 ? e1 : eStart];
        float4 x0 = ((const float4*)(Xp + (size_t)c0 * D))[l];
        float4 x1 = ((const float4*)(Xp + (size_t)c1 * D))[l];

        float p0 = x0.x * xr.x + x0.y * xr.y + x0.z * xr.z + x0.w * xr.w;
        float p1 = x1.x * xr.x + x1.y * xr.y + x1.z * xr.z + x1.w * xr.w;
#pragma unroll
        for (int off = 8; off > 0; off >>= 1) {  // reduce within 16-lane group
            p0 += __shfl_xor(p0, off, 64);
            p1 += __shfl_xor(p1, off, 64);
        }
        float s0 = v0 ? p0 * attn : 0.f;
        float s1 = v1 ? p1 * attn : 0.f;

        acc0.x = fmaf(s0, x0.x, acc0.x); acc0.y = fmaf(s0, x0.y, acc0.y);
        acc0.z = fmaf(s0, x0.z, acc0.z); acc0.w = fmaf(s0, x0.w, acc0.w);
        acc1.x = fmaf(s1, x1.x, acc1.x); acc1.y = fmaf(s1, x1.y, acc1.y);
        acc1.z = fmaf(s1, x1.z, acc1.z); acc1.w = fmaf(s1, x1.w, acc1.w);
    }

    acc0.x += acc1.x; acc0.y += acc1.y; acc0.z += acc1.z; acc0.w += acc1.w;
    // combine the 4 group-local accumulators (lanes l, l+16, l+32, l+48)
#pragma unroll
    for (int off = 16; off <= 32; off <<= 1) {
        acc0.x += __shfl_xor(acc0.x, off, 64);
        acc0.y += __shfl_xor(acc0.y, off, 64);
        acc0.z += __shfl_xor(acc0.z, off, 64);
        acc0.w += __shfl_xor(acc0.w, off, 64);
    }
    if (lane < 16) ((float4*)(out + (size_t)node * D))[lane] = acc0;
}

extern "C" void kernel_launch(void* const* d_in, const int* in_sizes, int n_in,
                              void* d_out, int out_size, void* d_ws, size_t ws_size,
                              hipStream_t stream) {
    const float* X    = (const float*)d_in[0];
    const float* W    = (const float*)d_in[1];
    const float* attn = (const float*)d_in[2];
    const int*   row  = (const int*)d_in[3];
    const int*   col  = (const int*)d_in[4];
    float* out = (float*)d_out;

    int nNodes = in_sizes[0] / D;
    int nEdges = in_sizes[3];

    // workspace layout: Xp [nNodes*D] | rowptr [nNodes+1]
    float* Xp     = (float*)d_ws;
    int*   rowptr = (int*)(Xp + (size_t)nNodes * D);

    gemm_kernel<<<1024, 256, 0, stream>>>(X, W, Xp, nNodes);
    rowptr_kernel<<<(nEdges + 255) / 256, 256, 0, stream>>>(row, rowptr, nNodes, nEdges);
    fused_kernel<<<(nNodes + 3) / 4, 256, 0, stream>>>(Xp, rowptr, col, attn, out, nNodes);
}

// Round 4
// 115.558 us; speedup vs baseline: 2.3257x; 1.0381x over previous
//
#include <hip/hip_runtime.h>
#include <hip/hip_bf16.h>

#define D 64

// ---------------------------------------------------------------------------
// bf16x8 (uint4) -> 8 floats. Element 0 is the low 16 bits of u.x.
// ---------------------------------------------------------------------------
__device__ __forceinline__ void bf16x8_to_f32(uint4 u, float f[8]) {
    union { unsigned int i; float x; } t;
    t.i = u.x << 16;          f[0] = t.x;
    t.i = u.x & 0xFFFF0000u;  f[1] = t.x;
    t.i = u.y << 16;          f[2] = t.x;
    t.i = u.y & 0xFFFF0000u;  f[3] = t.x;
    t.i = u.z << 16;          f[4] = t.x;
    t.i = u.z & 0xFFFF0000u;  f[5] = t.x;
    t.i = u.w << 16;          f[6] = t.x;
    t.i = u.w & 0xFFFF0000u;  f[7] = t.x;
}

// ---------------------------------------------------------------------------
// Kernel 1: Xp = bf16(X @ W). One wave per row; lane d holds W column d in
// 64 VGPRs; X row read wave-uniformly -> pure FMA. Stores bf16 (128 B/row).
// ---------------------------------------------------------------------------
__global__ __launch_bounds__(256) void gemm_kernel(const float* __restrict__ X,
                                                   const float* __restrict__ W,
                                                   __hip_bfloat16* __restrict__ Xp,
                                                   int nNodes) {
    int lane = threadIdx.x & 63;
    int wave = (blockIdx.x * 256 + threadIdx.x) >> 6;
    int nWaves = gridDim.x * 4;

    float w[D];
#pragma unroll
    for (int k = 0; k < D; ++k) w[k] = W[k * D + lane];

    for (int r = wave; r < nNodes; r += nWaves) {
        int row = __builtin_amdgcn_readfirstlane(r);
        const float4* xr = (const float4*)(X + (size_t)row * D);
        float acc = 0.f;
#pragma unroll
        for (int k4 = 0; k4 < D / 4; ++k4) {
            float4 xv = xr[k4];
            acc = fmaf(xv.x, w[4 * k4 + 0], acc);
            acc = fmaf(xv.y, w[4 * k4 + 1], acc);
            acc = fmaf(xv.z, w[4 * k4 + 2], acc);
            acc = fmaf(xv.w, w[4 * k4 + 3], acc);
        }
        Xp[(size_t)row * D + lane] = __float2bfloat16(acc);
    }
}

// ---------------------------------------------------------------------------
// Kernel 2: CSR row pointers from sorted `row`.
// ---------------------------------------------------------------------------
__global__ __launch_bounds__(256) void rowptr_kernel(const int* __restrict__ row,
                                                     int* __restrict__ rowptr,
                                                     int nNodes, int nEdges) {
    int e = blockIdx.x * 256 + threadIdx.x;
    if (e >= nEdges) return;
    int r = row[e];
    int rprev = (e == 0) ? -1 : row[e - 1];
    for (int q = rprev + 1; q <= r; ++q) rowptr[q] = e;
    if (e == nEdges - 1) {
        for (int q = r + 1; q <= nNodes; ++q) rowptr[q] = nEdges;
    }
}

// ---------------------------------------------------------------------------
// Kernel 3: fused SDDMM + SpMM. One wave per destination node.
// 8 groups x 8 lanes; each group owns one edge; lane j of a group holds dims
// 8j..8j+7 as one uint4 (8 bf16, 16 B). Inner loop: fixed-trip chunks of 16
// edges (2 independent gathers in flight), masked by cidx = -1.
// No atomics; coalesced 256 B store per node.
// ---------------------------------------------------------------------------
__global__ __launch_bounds__(256) void fused_kernel(const __hip_bfloat16* __restrict__ Xp,
                                                    const int* __restrict__ rowptr,
                                                    const int* __restrict__ col,
                                                    const float* __restrict__ attn_w,
                                                    float* __restrict__ out,
                                                    int nNodes) {
    int lane = threadIdx.x & 63;
    int node = (blockIdx.x * 256 + threadIdx.x) >> 6;
    if (node >= nNodes) return;
    int g = lane >> 3;      // edge group 0..7
    int j = lane & 7;       // dim chunk: dims 8j..8j+7

    int eStart = rowptr[node];
    int eEnd   = rowptr[node + 1];
    float attn = attn_w[0];

    const uint4* XpV = (const uint4*)Xp;          // row stride = 8 uint4 (128 B)
    float xr[8];
    bf16x8_to_f32(XpV[(size_t)node * 8 + j], xr); // dst row chunk

    float acc[8] = {0.f, 0.f, 0.f, 0.f, 0.f, 0.f, 0.f, 0.f};

    for (int cb = eStart; cb < eEnd; cb += 64) {
        int myE = cb + lane;
        int cidx = (myE < eEnd) ? col[myE] : -1;  // -1 marks invalid slot
        int nrem = eEnd - cb;

#pragma unroll
        for (int m = 0; m < 4; ++m) {
            if (16 * m >= nrem) break;
            // two independent 8-edge steps: slots 16m+g and 16m+8+g
            int c0 = __shfl(cidx, 16 * m + g, 64);
            int c1 = __shfl(cidx, 16 * m + 8 + g, 64);
            bool v0 = c0 >= 0, v1 = c1 >= 0;
            uint4 u0 = XpV[(size_t)(v0 ? c0 : 0) * 8 + j];
            uint4 u1 = XpV[(size_t)(v1 ? c1 : 0) * 8 + j];
            float x0[8], x1[8];
            bf16x8_to_f32(u0, x0);
            bf16x8_to_f32(u1, x1);

            float p0 = 0.f, p1 = 0.f;
#pragma unroll
            for (int q = 0; q < 8; ++q) { p0 = fmaf(xr[q], x0[q], p0);
                                          p1 = fmaf(xr[q], x1[q], p1); }
#pragma unroll
            for (int off = 1; off < 8; off <<= 1) { p0 += __shfl_xor(p0, off, 64);
                                                    p1 += __shfl_xor(p1, off, 64); }
            float s0 = v0 ? p0 * attn : 0.f;
            float s1 = v1 ? p1 * attn : 0.f;
#pragma unroll
            for (int q = 0; q < 8; ++q) { acc[q] = fmaf(s0, x0[q], acc[q]);
                                          acc[q] = fmaf(s1, x1[q], acc[q]); }
        }
    }

    // combine the 8 group-local accumulators: dims 8j..8j+7 live in lanes j+8g
#pragma unroll
    for (int off = 8; off < 64; off <<= 1)
#pragma unroll
        for (int q = 0; q < 8; ++q) acc[q] += __shfl_xor(acc[q], off, 64);

    if (g == 0) {
        float4* o = (float4*)(out + (size_t)node * D + 8 * j);
        o[0] = make_float4(acc[0], acc[1], acc[2], acc[3]);
        o[1] = make_float4(acc[4], acc[5], acc[6], acc[7]);
    }
}

extern "C" void kernel_launch(void* const* d_in, const int* in_sizes, int n_in,
                              void* d_out, int out_size, void* d_ws, size_t ws_size,
                              hipStream_t stream) {
    const float* X    = (const float*)d_in[0];
    const float* W    = (const float*)d_in[1];
    const float* attn = (const float*)d_in[2];
    const int*   row  = (const int*)d_in[3];
    const int*   col  = (const int*)d_in[4];
    float* out = (float*)d_out;

    int nNodes = in_sizes[0] / D;
    int nEdges = in_sizes[3];

    // workspace layout: Xp_bf16 [nNodes*D] | rowptr [nNodes+1]
    __hip_bfloat16* Xp = (__hip_bfloat16*)d_ws;
    int* rowptr = (int*)((char*)d_ws + (size_t)nNodes * D * sizeof(__hip_bfloat16));

    gemm_kernel<<<1024, 256, 0, stream>>>(X, W, Xp, nNodes);
    rowptr_kernel<<<(nEdges + 255) / 256, 256, 0, stream>>>(row, rowptr, nNodes, nEdges);
    fused_kernel<<<(nNodes + 3) / 4, 256, 0, stream>>>(Xp, rowptr, col, attn, out, nNodes);
}

// Round 5
// 106.208 us; speedup vs baseline: 2.5304x; 1.0880x over previous
//
#include <hip/hip_runtime.h>
#include <hip/hip_fp16.h>

#define D 64

// ---------------------------------------------------------------------------
// 8 f16 packed in a uint4 -> 8 floats.
// ---------------------------------------------------------------------------
__device__ __forceinline__ void h8_to_f32(uint4 u, float f[8]) {
    float2 t;
    t = __half22float2(*(const __half2*)&u.x); f[0] = t.x; f[1] = t.y;
    t = __half22float2(*(const __half2*)&u.y); f[2] = t.x; f[3] = t.y;
    t = __half22float2(*(const __half2*)&u.z); f[4] = t.x; f[5] = t.y;
    t = __half22float2(*(const __half2*)&u.w); f[6] = t.x; f[7] = t.y;
}

// ---------------------------------------------------------------------------
// Kernel 1 (merged): blocks [0, gemmBlocks) compute Xp = f16(X @ W) -- one
// wave per row, W column in 64 VGPRs, X row read wave-uniformly.
// Blocks [gemmBlocks, ...) build CSR rowptr from sorted `row`.
// ---------------------------------------------------------------------------
__global__ __launch_bounds__(256) void prep_kernel(const float* __restrict__ X,
                                                   const float* __restrict__ W,
                                                   const int* __restrict__ row,
                                                   __half* __restrict__ Xp,
                                                   int* __restrict__ rowptr,
                                                   int nNodes, int nEdges,
                                                   int gemmBlocks) {
    if ((int)blockIdx.x >= gemmBlocks) {
        // ---- rowptr path ----
        int e = (blockIdx.x - gemmBlocks) * 256 + threadIdx.x;
        if (e >= nEdges) return;
        int r = row[e];
        int rprev = (e == 0) ? -1 : row[e - 1];
        for (int q = rprev + 1; q <= r; ++q) rowptr[q] = e;
        if (e == nEdges - 1) {
            for (int q = r + 1; q <= nNodes; ++q) rowptr[q] = nEdges;
        }
        return;
    }
    // ---- GEMM path ----
    int lane = threadIdx.x & 63;
    int wave = (blockIdx.x * 256 + threadIdx.x) >> 6;
    int nWaves = gemmBlocks * 4;

    float w[D];
#pragma unroll
    for (int k = 0; k < D; ++k) w[k] = W[k * D + lane];

    for (int r = wave; r < nNodes; r += nWaves) {
        int rr = __builtin_amdgcn_readfirstlane(r);       // uniform -> scalar loads
        const float4* xr = (const float4*)(X + (size_t)rr * D);
        float acc = 0.f;
#pragma unroll
        for (int k4 = 0; k4 < D / 4; ++k4) {
            float4 xv = xr[k4];
            acc = fmaf(xv.x, w[4 * k4 + 0], acc);
            acc = fmaf(xv.y, w[4 * k4 + 1], acc);
            acc = fmaf(xv.z, w[4 * k4 + 2], acc);
            acc = fmaf(xv.w, w[4 * k4 + 3], acc);
        }
        Xp[(size_t)rr * D + lane] = __float2half(acc);
    }
}

// ---------------------------------------------------------------------------
// Kernel 2: fused SDDMM + SpMM. One 8-lane group per destination node
// (8 nodes per wave). Lane j of a group holds dims 8j..8j+7 (one uint4 of
// f16). Per iteration each group processes 4 edges with 4 independent
// gathers in flight; dot reduce = 3 shfl steps inside the group; NO
// cross-group epilogue. Coalesced 2 KB store per wave. No atomics.
// ---------------------------------------------------------------------------
__global__ __launch_bounds__(256) void fused_kernel(const __half* __restrict__ Xp,
                                                    const int* __restrict__ rowptr,
                                                    const int* __restrict__ col,
                                                    const float* __restrict__ attn_w,
                                                    float* __restrict__ out,
                                                    int nNodes) {
    int lane = threadIdx.x & 63;
    int waveId = (blockIdx.x * 256 + threadIdx.x) >> 6;
    int g = lane >> 3;        // node slot within wave, 0..7
    int j = lane & 7;         // dim chunk: dims 8j..8j+7

    int node = waveId * 8 + g;
    bool active = node < nNodes;
    int nd = active ? node : (nNodes - 1);

    int eStart = rowptr[nd];
    int eEnd   = active ? rowptr[nd + 1] : eStart;   // inactive: zero-trip loop
    float attn = attn_w[0];

    const uint4* XpV = (const uint4*)Xp;             // row stride = 8 uint4 (128 B)
    float xr[8];
    h8_to_f32(XpV[(size_t)nd * 8 + j], xr);

    float acc[8] = {0.f, 0.f, 0.f, 0.f, 0.f, 0.f, 0.f, 0.f};

    for (int e = eStart; e < eEnd; e += 4) {
        bool v[4];
        int  c[4];
#pragma unroll
        for (int u = 0; u < 4; ++u) {
            int ee = e + u;
            v[u] = ee < eEnd;
            c[u] = col[v[u] ? ee : eStart];          // group-uniform address
        }
        uint4 raw[4];
#pragma unroll
        for (int u = 0; u < 4; ++u)                  // 4 independent gathers
            raw[u] = XpV[(size_t)c[u] * 8 + j];

        float xf[4][8];
        float p[4];
#pragma unroll
        for (int u = 0; u < 4; ++u) {
            h8_to_f32(raw[u], xf[u]);
            float s = 0.f;
#pragma unroll
            for (int q = 0; q < 8; ++q) s = fmaf(xr[q], xf[u][q], s);
            p[u] = s;
        }
#pragma unroll
        for (int off = 1; off < 8; off <<= 1) {      // reduce within 8-lane group
#pragma unroll
            for (int u = 0; u < 4; ++u) p[u] += __shfl_xor(p[u], off, 64);
        }
#pragma unroll
        for (int u = 0; u < 4; ++u) {
            float s = v[u] ? p[u] * attn : 0.f;
#pragma unroll
            for (int q = 0; q < 8; ++q) acc[q] = fmaf(s, xf[u][q], acc[q]);
        }
    }

    if (active) {
        float4* o = (float4*)(out + (size_t)node * D + 8 * j);
        o[0] = make_float4(acc[0], acc[1], acc[2], acc[3]);
        o[1] = make_float4(acc[4], acc[5], acc[6], acc[7]);
    }
}

extern "C" void kernel_launch(void* const* d_in, const int* in_sizes, int n_in,
                              void* d_out, int out_size, void* d_ws, size_t ws_size,
                              hipStream_t stream) {
    const float* X    = (const float*)d_in[0];
    const float* W    = (const float*)d_in[1];
    const float* attn = (const float*)d_in[2];
    const int*   row  = (const int*)d_in[3];
    const int*   col  = (const int*)d_in[4];
    float* out = (float*)d_out;

    int nNodes = in_sizes[0] / D;
    int nEdges = in_sizes[3];

    // workspace layout: Xp_f16 [nNodes*D] | rowptr [nNodes+1]
    __half* Xp  = (__half*)d_ws;
    int* rowptr = (int*)((char*)d_ws + (size_t)nNodes * D * sizeof(__half));

    int gemmBlocks = 1024;
    int rpBlocks   = (nEdges + 255) / 256;
    prep_kernel<<<gemmBlocks + rpBlocks, 256, 0, stream>>>(X, W, row, Xp, rowptr,
                                                           nNodes, nEdges, gemmBlocks);

    int waves = (nNodes + 7) / 8;                    // 8 nodes per wave
    fused_kernel<<<(waves + 3) / 4, 256, 0, stream>>>(Xp, rowptr, col, attn, out, nNodes);
}

// Round 6
// 104.817 us; speedup vs baseline: 2.5640x; 1.0133x over previous
//
#include <hip/hip_runtime.h>
#include <hip/hip_fp16.h>

#define D 64

typedef _Float16 h16;
typedef h16 h16x2 __attribute__((ext_vector_type(2)));

__device__ __forceinline__ h16x2 u2h(unsigned int u) {
    union { unsigned int i; h16x2 h; } t; t.i = u; return t.h;
}

// dot of 8 f16 pairs (two uint4-packed rows), f32 accumulate
__device__ __forceinline__ float dot8_f16(uint4 a, uint4 b, float c) {
#if __has_builtin(__builtin_amdgcn_fdot2)
    c = __builtin_amdgcn_fdot2(u2h(a.x), u2h(b.x), c, false);
    c = __builtin_amdgcn_fdot2(u2h(a.y), u2h(b.y), c, false);
    c = __builtin_amdgcn_fdot2(u2h(a.z), u2h(b.z), c, false);
    c = __builtin_amdgcn_fdot2(u2h(a.w), u2h(b.w), c, false);
    return c;
#else
    float2 t;
    t = __half22float2(*(const __half2*)&a.x); float2 s = __half22float2(*(const __half2*)&b.x);
    c = fmaf(t.x, s.x, c); c = fmaf(t.y, s.y, c);
    t = __half22float2(*(const __half2*)&a.y); s = __half22float2(*(const __half2*)&b.y);
    c = fmaf(t.x, s.x, c); c = fmaf(t.y, s.y, c);
    t = __half22float2(*(const __half2*)&a.z); s = __half22float2(*(const __half2*)&b.z);
    c = fmaf(t.x, s.x, c); c = fmaf(t.y, s.y, c);
    t = __half22float2(*(const __half2*)&a.w); s = __half22float2(*(const __half2*)&b.w);
    c = fmaf(t.x, s.x, c); c = fmaf(t.y, s.y, c);
    return c;
#endif
}

__device__ __forceinline__ void h8_to_f32(uint4 u, float f[8]) {
    float2 t;
    t = __half22float2(*(const __half2*)&u.x); f[0] = t.x; f[1] = t.y;
    t = __half22float2(*(const __half2*)&u.y); f[2] = t.x; f[3] = t.y;
    t = __half22float2(*(const __half2*)&u.z); f[4] = t.x; f[5] = t.y;
    t = __half22float2(*(const __half2*)&u.w); f[6] = t.x; f[7] = t.y;
}

// ---------------------------------------------------------------------------
// Kernel 1 (merged): blocks [0, gemmBlocks) compute Xp = f16(X @ W);
// blocks [gemmBlocks, ...) build CSR rowptr from sorted `row`.
// ---------------------------------------------------------------------------
__global__ __launch_bounds__(256) void prep_kernel(const float* __restrict__ X,
                                                   const float* __restrict__ W,
                                                   const int* __restrict__ row,
                                                   __half* __restrict__ Xp,
                                                   int* __restrict__ rowptr,
                                                   int nNodes, int nEdges,
                                                   int gemmBlocks) {
    if ((int)blockIdx.x >= gemmBlocks) {
        int e = (blockIdx.x - gemmBlocks) * 256 + threadIdx.x;
        if (e >= nEdges) return;
        int r = row[e];
        int rprev = (e == 0) ? -1 : row[e - 1];
        for (int q = rprev + 1; q <= r; ++q) rowptr[q] = e;
        if (e == nEdges - 1) {
            for (int q = r + 1; q <= nNodes; ++q) rowptr[q] = nEdges;
        }
        return;
    }
    int lane = threadIdx.x & 63;
    int wave = (blockIdx.x * 256 + threadIdx.x) >> 6;
    int nWaves = gemmBlocks * 4;

    float w[D];
#pragma unroll
    for (int k = 0; k < D; ++k) w[k] = W[k * D + lane];

    for (int r = wave; r < nNodes; r += nWaves) {
        int rr = __builtin_amdgcn_readfirstlane(r);
        const float4* xr = (const float4*)(X + (size_t)rr * D);
        float acc = 0.f;
#pragma unroll
        for (int k4 = 0; k4 < D / 4; ++k4) {
            float4 xv = xr[k4];
            acc = fmaf(xv.x, w[4 * k4 + 0], acc);
            acc = fmaf(xv.y, w[4 * k4 + 1], acc);
            acc = fmaf(xv.z, w[4 * k4 + 2], acc);
            acc = fmaf(xv.w, w[4 * k4 + 3], acc);
        }
        Xp[(size_t)rr * D + lane] = __float2half(acc);
    }
}

// ---------------------------------------------------------------------------
// Kernel 2: fused SDDMM + SpMM, software-pipelined.
// One 8-lane group per destination node (8 nodes/wave); lane j holds dims
// 8j..8j+7 (one uint4 of f16). Batches of 4 edges; batch i+1's col loads and
// row gathers are issued BEFORE batch i is consumed, so gather latency
// overlaps compute. Dot = 4 x v_dot2_f32_f16 + 3-shfl in-group reduce.
// attn applied once in the epilogue. No atomics; coalesced stores.
// ---------------------------------------------------------------------------
__global__ __launch_bounds__(256) void fused_kernel(const __half* __restrict__ Xp,
                                                    const int* __restrict__ rowptr,
                                                    const int* __restrict__ col,
                                                    const float* __restrict__ attn_w,
                                                    float* __restrict__ out,
                                                    int nNodes) {
    int lane = threadIdx.x & 63;
    int waveId = (blockIdx.x * 256 + threadIdx.x) >> 6;
    int g = lane >> 3;        // node slot within wave
    int j = lane & 7;         // dim chunk: dims 8j..8j+7

    int node = waveId * 8 + g;
    bool active = node < nNodes;
    int nd = active ? node : 0;

    int eStart = rowptr[nd];
    int eEnd   = active ? rowptr[nd + 1] : eStart;

    const uint4* XpV = (const uint4*)Xp;              // row stride = 8 uint4
    uint4 xr = XpV[(size_t)nd * 8 + j];               // dst row chunk (f16)

    float acc[8] = {0.f, 0.f, 0.f, 0.f, 0.f, 0.f, 0.f, 0.f};

    // prologue: load batch 0 (safe index 0 for out-of-range slots)
    bool v[4]; uint4 raw[4];
#pragma unroll
    for (int u = 0; u < 4; ++u) {
        int ee = eStart + u;
        v[u] = ee < eEnd;
        int cc = col[v[u] ? ee : 0];
        raw[u] = XpV[(size_t)cc * 8 + j];
    }

    for (int e = eStart; e < eEnd; e += 4) {
        // ---- issue batch i+1 loads first (overlap with batch i compute) ----
        bool v2[4]; uint4 raw2[4];
#pragma unroll
        for (int u = 0; u < 4; ++u) {
            int ee = e + 4 + u;
            v2[u] = ee < eEnd;
            int cc = col[v2[u] ? ee : 0];
            raw2[u] = XpV[(size_t)cc * 8 + j];
        }
        // ---- consume batch i ----
        float p[4];
#pragma unroll
        for (int u = 0; u < 4; ++u) p[u] = dot8_f16(xr, raw[u], 0.f);
#pragma unroll
        for (int off = 1; off < 8; off <<= 1)
#pragma unroll
            for (int u = 0; u < 4; ++u) p[u] += __shfl_xor(p[u], off, 64);
#pragma unroll
        for (int u = 0; u < 4; ++u) {
            float s = v[u] ? p[u] : 0.f;                 // attn deferred to epilogue
            float xf[8]; h8_to_f32(raw[u], xf);
#pragma unroll
            for (int q = 0; q < 8; ++q) acc[q] = fmaf(s, xf[q], acc[q]);
        }
        // ---- rotate ----
#pragma unroll
        for (int u = 0; u < 4; ++u) { v[u] = v2[u]; raw[u] = raw2[u]; }
    }

    if (active) {
        float attn = attn_w[0];
        float4* o = (float4*)(out + (size_t)node * D + 8 * j);
        o[0] = make_float4(attn * acc[0], attn * acc[1], attn * acc[2], attn * acc[3]);
        o[1] = make_float4(attn * acc[4], attn * acc[5], attn * acc[6], attn * acc[7]);
    }
}

extern "C" void kernel_launch(void* const* d_in, const int* in_sizes, int n_in,
                              void* d_out, int out_size, void* d_ws, size_t ws_size,
                              hipStream_t stream) {
    const float* X    = (const float*)d_in[0];
    const float* W    = (const float*)d_in[1];
    const float* attn = (const float*)d_in[2];
    const int*   row  = (const int*)d_in[3];
    const int*   col  = (const int*)d_in[4];
    float* out = (float*)d_out;

    int nNodes = in_sizes[0] / D;
    int nEdges = in_sizes[3];

    // workspace layout: Xp_f16 [nNodes*D] | rowptr [nNodes+1]
    __half* Xp  = (__half*)d_ws;
    int* rowptr = (int*)((char*)d_ws + (size_t)nNodes * D * sizeof(__half));

    int gemmBlocks = 1024;
    int rpBlocks   = (nEdges + 255) / 256;
    prep_kernel<<<gemmBlocks + rpBlocks, 256, 0, stream>>>(X, W, row, Xp, rowptr,
                                                           nNodes, nEdges, gemmBlocks);

    int waves = (nNodes + 7) / 8;                        // 8 nodes per wave
    fused_kernel<<<(waves + 3) / 4, 256, 0, stream>>>(Xp, rowptr, col, attn, out, nNodes);
}